// Round 3
// baseline (16373.535 us; speedup 1.0000x reference)
//
#include <hip/hip_runtime.h>
#include <math.h>

#define Nn 131072
#define Ee 524288
#define LROW 224              // limb-plane row stride (shorts): msg[0,100) pad[100,112) h[112,212) pad[212,224)

typedef __attribute__((ext_vector_type(8))) short short8;
typedef __attribute__((ext_vector_type(4))) float f32x4;
typedef unsigned short ushort_t;
typedef unsigned int uint32;

__device__ __forceinline__ f32x4 mfma16(short8 a, short8 b, f32x4 c) {
    return __builtin_amdgcn_mfma_f32_16x16x32_bf16(a, b, c, 0, 0, 0);
}

__device__ __forceinline__ uint32 rne_bf16(float x) {
    uint32 u = __float_as_uint(x);
    return (u + 0x7FFFu + ((u >> 16) & 1u)) >> 16;
}

// fp32 -> 3 bf16 limbs (hi, mid, lo). For normal fp32 this decomposition is
// EXACT (8+8+8 mantissa bits; residual subtractions are Sterbenz-exact), and
// (l+m)+h reconstructs x exactly in fp32. The limb planes are therefore a
// lossless representation of the fp32 h state.
__device__ __forceinline__ void split3(float x, uint32& h, uint32& m, uint32& l) {
    h = rne_bf16(x);
    float hf = __uint_as_float(h << 16);
    float r1 = x - hf;
    m = rne_bf16(r1);
    float mf = __uint_as_float(m << 16);
    float r2 = r1 - mf;
    l = rne_bf16(r2);
}

__device__ __forceinline__ float limb2f(ushort_t u) {
    return __uint_as_float((uint32)u << 16);
}

// ---------------------------------------------------------------- diag / zero
__global__ void diag_kernel(float* out, float val) {
    int n = blockIdx.x * 256 + threadIdx.x;
    if (n < Nn) out[n] = (n == 0) ? val : 0.f;
}
__global__ void zero_ints(int* p, int n) {
    int i = blockIdx.x * 256 + threadIdx.x;
    if (i < n) p[i] = 0;
}
__global__ void zero_short8(ushort_t* p, long n8) {
    long i = (long)blockIdx.x * 256 + threadIdx.x;
    if (i < n8) {
        short8 zz = {0, 0, 0, 0, 0, 0, 0, 0};
        *(short8*)(p + i * 8) = zz;
    }
}

// ---------------------------------------------------------------- CSR build
__global__ void hist_kernel(const int* __restrict__ er, const int* __restrict__ ec,
                            int* __restrict__ cnt_f, int* __restrict__ cnt_b) {
    int e = blockIdx.x * 256 + threadIdx.x;
    atomicAdd(&cnt_f[er[e]], 1);
    atomicAdd(&cnt_b[ec[e]], 1);
}

// two independent scans in one launch (block 0: forward, block 1: backward)
__global__ __launch_bounds__(1024) void scan2_kernel(
    const int* __restrict__ cnt_f, const int* __restrict__ cnt_b,
    int* __restrict__ ptr_f, int* __restrict__ ptr_b, int n) {
    const int* cnt = blockIdx.x ? cnt_b : cnt_f;
    int* ptr = blockIdx.x ? ptr_b : ptr_f;
    __shared__ int sums[1024];
    int t = threadIdx.x;
    int chunk = n >> 10;
    int base = t * chunk;
    int s = 0;
    for (int i = 0; i < chunk; i++) s += cnt[base + i];
    sums[t] = s;
    __syncthreads();
    for (int off = 1; off < 1024; off <<= 1) {
        int v = (t >= off) ? sums[t - off] : 0;
        __syncthreads();
        sums[t] += v;
        __syncthreads();
    }
    int run = (t == 0) ? 0 : sums[t - 1];
    for (int i = 0; i < chunk; i++) { ptr[base + i] = run; run += cnt[base + i]; }
    if (t == 1023) ptr[n] = run;
}

// fill advances ptr in place; afterwards start(r) = (r ? ptr[r-1] : 0), end(r) = ptr[r]
__global__ void fill_kernel(const int* __restrict__ er, const int* __restrict__ ec,
                            int* __restrict__ ptr_f, int* __restrict__ ptr_b,
                            int* __restrict__ src_f, int* __restrict__ src_b) {
    int e = blockIdx.x * 256 + threadIdx.x;
    int r = er[e], c = ec[e];
    int p = atomicAdd(&ptr_f[r], 1); src_f[p] = c;
    int q = atomicAdd(&ptr_b[c], 1); src_b[q] = r;
}

// ---------------------------------------------------------------- weight prep
// GRU: Wt[c=4d+g][k], c<448 (28 tiles). k layout matches limb planes:
// k<100: Wih[., k], 112<=k<212: Whh[., k-112], else 0.
__global__ void prep_gru_w(const float* __restrict__ Wih, const float* __restrict__ Whh,
                           const float* __restrict__ bih, const float* __restrict__ bhh,
                           ushort_t* __restrict__ W0, ushort_t* __restrict__ W1,
                           ushort_t* __restrict__ W2, float* __restrict__ bg) {
    int gid = blockIdx.x * 256 + threadIdx.x;
    if (gid >= 448 * 224) return;
    int c = gid / 224, k = gid - c * 224;
    int d = c >> 2, g = c & 3;
    float w = 0.f;
    if (d < 100) {
        if (k < 100) {
            if (g == 0)      w = Wih[d * 100 + k];
            else if (g == 1) w = Wih[(100 + d) * 100 + k];
            else if (g == 2) w = Wih[(200 + d) * 100 + k];
        } else if (k >= 112 && k < 212) {
            int kk = k - 112;
            if (g == 0)      w = Whh[d * 100 + kk];
            else if (g == 1) w = Whh[(100 + d) * 100 + kk];
            else if (g == 3) w = Whh[(200 + d) * 100 + kk];
        }
    }
    uint32 h, m, l; split3(w, h, m, l);
    W0[gid] = (ushort_t)h; W1[gid] = (ushort_t)m; W2[gid] = (ushort_t)l;
    if (k == 0) {
        float b = 0.f;
        if (d < 100) {
            if (g == 0)      b = bih[d] + bhh[d];
            else if (g == 1) b = bih[100 + d] + bhh[100 + d];
            else if (g == 2) b = bih[200 + d];
            else             b = bhh[200 + d];
        }
        bg[c] = b;
    }
}

// msg MLP: W1t[c<64][k<128] (c=hidden col, k=h dim), W2t[c<112][k<64]
__global__ void prep_msg_w(const float* __restrict__ W1, const float* __restrict__ b1,
                           const float* __restrict__ W2, const float* __restrict__ b2,
                           ushort_t* __restrict__ A0, ushort_t* __restrict__ A1,
                           ushort_t* __restrict__ A2, float* __restrict__ b1p,
                           ushort_t* __restrict__ B0, ushort_t* __restrict__ B1,
                           ushort_t* __restrict__ B2, float* __restrict__ b2p) {
    int gid = blockIdx.x * 256 + threadIdx.x;
    if (gid < 8192) {
        int c = gid >> 7, k = gid & 127;
        float w = (c < 50 && k < 100) ? W1[k * 50 + c] : 0.f;
        uint32 h, m, l; split3(w, h, m, l);
        A0[gid] = (ushort_t)h; A1[gid] = (ushort_t)m; A2[gid] = (ushort_t)l;
        if (k == 0) b1p[c] = (c < 50) ? b1[c] : 0.f;
    } else if (gid < 8192 + 7168) {
        int t = gid - 8192;
        int c = t >> 6, k = t & 63;
        float w = (c < 100 && k < 50) ? W2[k * 100 + c] : 0.f;
        uint32 h, m, l; split3(w, h, m, l);
        B0[t] = (ushort_t)h; B1[t] = (ushort_t)m; B2[t] = (ushort_t)l;
        if (k == 0) b2p[c] = (c < 100) ? b2[c] : 0.f;
    }
}

// ---------------------------------------------------------------- init h
// h0 = feat @ init_W + b, split to limbs at k in [112,212) of the limb planes.
__global__ void init_h_kernel(const float* __restrict__ feat, const float* __restrict__ W,
                              const float* __restrict__ b,
                              ushort_t* __restrict__ L0, ushort_t* __restrict__ L1,
                              ushort_t* __restrict__ L2) {
    int gid = blockIdx.x * 256 + threadIdx.x;   // N*100
    if (gid >= Nn * 100) return;
    int n = gid / 100, d = gid - n * 100;
    float acc = b[d];
#pragma unroll
    for (int k = 0; k < 4; k++) acc += feat[n * 4 + k] * W[k * 100 + d];
    uint32 h, m, l; split3(acc, h, m, l);
    size_t a = (size_t)n * LROW + 112 + d;
    L0[a] = (ushort_t)h; L1[a] = (ushort_t)m; L2[a] = (ushort_t)l;
}

// ---------------------------------------------------------------- msg MLP (MFMA)
// fm = relu(h @ W1 + b1) @ W2 + b2 ; computed transposed: D[c][n].
// h inputs come straight from the limb planes (no fp32 load, no split3).
__global__ __launch_bounds__(256, 2) void msg_mfma(
    const ushort_t* __restrict__ L0, const ushort_t* __restrict__ L1,
    const ushort_t* __restrict__ L2,
    const ushort_t* __restrict__ A0, const ushort_t* __restrict__ A1,
    const ushort_t* __restrict__ A2, const float* __restrict__ b1p,
    const ushort_t* __restrict__ B0, const ushort_t* __restrict__ B1,
    const ushort_t* __restrict__ B2, const float* __restrict__ b2p,
    float* __restrict__ fm) {
    __shared__ ushort_t C1[3][64][72];
    const int tid = threadIdx.x;
    const int u = tid >> 6;          // wave = node tile
    const int lane = tid & 63;
    const int m = lane & 15, q = lane >> 4;
    const int n0 = blockIdx.x * 64;
    const int n = n0 + u * 16 + m;

    f32x4 z = {0.f, 0.f, 0.f, 0.f};
    f32x4 a1[4] = {z, z, z, z};

    const size_t hbase = (size_t)n * LROW + 112;
    for (int kc = 0; kc < 4; kc++) {
        int kb = kc * 32 + q * 8;
        // k in [kb, kb+8): real h for k<100, zeros for [100,112) pad;
        // kc==3 upper q over-reads into [224,240) = next row msg limbs /
        // tail pad — finite, and A-weights are zero for k>=100.
        short8 f0 = *(const short8*)(L0 + hbase + kb);
        short8 f1 = *(const short8*)(L1 + hbase + kb);
        short8 f2 = *(const short8*)(L2 + hbase + kb);
#pragma unroll
        for (int t = 0; t < 4; t++) {
            int off = (t * 16 + m) * 128 + kc * 32 + q * 8;
            short8 w0 = *(const short8*)(A0 + off);
            short8 w1 = *(const short8*)(A1 + off);
            short8 w2 = *(const short8*)(A2 + off);
            a1[t] = mfma16(w0, f0, a1[t]);
            a1[t] = mfma16(w0, f1, a1[t]);
            a1[t] = mfma16(w1, f0, a1[t]);
            a1[t] = mfma16(w0, f2, a1[t]);
            a1[t] = mfma16(w2, f0, a1[t]);
            a1[t] = mfma16(w1, f1, a1[t]);
        }
    }
    // epilogue 1: relu + split -> LDS
#pragma unroll
    for (int t = 0; t < 4; t++) {
        int c0 = t * 16 + 4 * q;
        float4 bb = *(const float4*)&b1p[c0];
        float v0 = fmaxf(a1[t][0] + bb.x, 0.f);
        float v1 = fmaxf(a1[t][1] + bb.y, 0.f);
        float v2 = fmaxf(a1[t][2] + bb.z, 0.f);
        float v3 = fmaxf(a1[t][3] + bb.w, 0.f);
        uint32 h0, m0, l0, h1, m1, l1, h2, m2, l2, h3, m3, l3;
        split3(v0, h0, m0, l0); split3(v1, h1, m1, l1);
        split3(v2, h2, m2, l2); split3(v3, h3, m3, l3);
        int nl = u * 16 + m;
        *(uint2*)&C1[0][nl][c0] = make_uint2(h0 | (h1 << 16), h2 | (h3 << 16));
        *(uint2*)&C1[1][nl][c0] = make_uint2(m0 | (m1 << 16), m2 | (m3 << 16));
        *(uint2*)&C1[2][nl][c0] = make_uint2(l0 | (l1 << 16), l2 | (l3 << 16));
    }
    __syncthreads();

    f32x4 a2[7] = {z, z, z, z, z, z, z};
    for (int kc = 0; kc < 2; kc++) {
        int nl = u * 16 + m;
        short8 c0f = *(const short8*)&C1[0][nl][kc * 32 + q * 8];
        short8 c1f = *(const short8*)&C1[1][nl][kc * 32 + q * 8];
        short8 c2f = *(const short8*)&C1[2][nl][kc * 32 + q * 8];
#pragma unroll
        for (int t = 0; t < 7; t++) {
            int off = (t * 16 + m) * 64 + kc * 32 + q * 8;
            short8 w0 = *(const short8*)(B0 + off);
            short8 w1 = *(const short8*)(B1 + off);
            short8 w2 = *(const short8*)(B2 + off);
            a2[t] = mfma16(w0, c0f, a2[t]);
            a2[t] = mfma16(w0, c1f, a2[t]);
            a2[t] = mfma16(w1, c0f, a2[t]);
            a2[t] = mfma16(w0, c2f, a2[t]);
            a2[t] = mfma16(w2, c0f, a2[t]);
            a2[t] = mfma16(w1, c1f, a2[t]);
        }
    }
#pragma unroll
    for (int t = 0; t < 7; t++) {
        int c0 = t * 16 + 4 * q;
        if (c0 < 100) {
            float4 bb = *(const float4*)&b2p[c0];
            float4 o;
            o.x = a2[t][0] + bb.x; o.y = a2[t][1] + bb.y;
            o.z = a2[t][2] + bb.z; o.w = a2[t][3] + bb.w;
            *(float4*)&fm[(size_t)n * 100 + c0] = o;
        }
    }
}

// ---------------------------------------------------------------- gather (CSR)
// Sums messages over incoming edges; stores the 3-limb split directly to the
// limb planes at k in [0,100) (gru's x = msg part).
__global__ void gather4(const float* __restrict__ fm, const int* __restrict__ ptr,
                        const int* __restrict__ idx,
                        ushort_t* __restrict__ L0, ushort_t* __restrict__ L1,
                        ushort_t* __restrict__ L2) {
    int gid = blockIdx.x * 256 + threadIdx.x;   // N*25
    int n = gid / 25, qq = (gid - n * 25) * 4;
    int s = (n == 0) ? 0 : ptr[n - 1];
    int e = ptr[n];
    float4 acc = {0.f, 0.f, 0.f, 0.f};
    for (int i = s; i < e; i++) {
        float4 v = *(const float4*)&fm[(size_t)idx[i] * 100 + qq];
        acc.x += v.x; acc.y += v.y; acc.z += v.z; acc.w += v.w;
    }
    uint32 h0, m0, l0, h1, m1, l1, h2, m2, l2, h3, m3, l3;
    split3(acc.x, h0, m0, l0); split3(acc.y, h1, m1, l1);
    split3(acc.z, h2, m2, l2); split3(acc.w, h3, m3, l3);
    size_t a = (size_t)n * LROW + qq;
    *(uint2*)&L0[a] = make_uint2(h0 | (h1 << 16), h2 | (h3 << 16));
    *(uint2*)&L1[a] = make_uint2(m0 | (m1 << 16), m2 | (m3 << 16));
    *(uint2*)&L2[a] = make_uint2(l0 | (l1 << 16), l2 | (l3 << 16));
}

// ---------------------------------------------------------------- GRU (MFMA) v7
// Pure consumer: x limbs pre-split in global (gather4: msg; init/own epilogue:
// h), weights pre-split. NO LDS tile, no split3 in the K-loop, no barriers in
// the K-loop. h state LIVES in the limb planes (lossless 3-bf16 decomposition
// of fp32). One __syncthreads before the epilogue: all waves of the block read
// all 64 rows' h limbs in the K-loop, and the epilogue overwrites them.
__global__ __launch_bounds__(256, 2) void gru_mfma(
    ushort_t* __restrict__ L0, ushort_t* __restrict__ L1,
    ushort_t* __restrict__ L2,
    const ushort_t* __restrict__ W0, const ushort_t* __restrict__ W1,
    const ushort_t* __restrict__ W2, const float* __restrict__ bg) {
    const int tid = threadIdx.x;
    const int wave = tid >> 6;
    const int lane = tid & 63;
    const int m = lane & 15, q = lane >> 4;
    const int n0 = blockIdx.x * 64;

    f32x4 z = {0.f, 0.f, 0.f, 0.f};
    f32x4 acc[7][4];
#pragma unroll
    for (int t = 0; t < 7; t++)
#pragma unroll
        for (int rf = 0; rf < 4; rf++) acc[t][rf] = z;

    int woff[7];
#pragma unroll
    for (int t = 0; t < 7; t++)
        woff[t] = ((t * 4 + wave) * 16 + m) * 224 + q * 8;

    const size_t abase = (size_t)(n0 + m) * LROW + q * 8;

#define GPASS(Wreg, Fr)                                          \
    _Pragma("unroll")                                            \
    for (int t = 0; t < 7; t++) {                                \
        _Pragma("unroll")                                        \
        for (int rf = 0; rf < 4; rf++)                           \
            acc[t][rf] = mfma16(Wreg[t], Fr[rf], acc[t][rf]);    \
    }

    for (int kc = 0; kc < 7; kc++) {
        const int ko = kc * 32;
        short8 f0[4], f1[4], f2[4];
#pragma unroll
        for (int rf = 0; rf < 4; rf++) {
            size_t a = abase + (size_t)rf * 16 * LROW + ko;
            f0[rf] = *(const short8*)(L0 + a);
            f1[rf] = *(const short8*)(L1 + a);
            f2[rf] = *(const short8*)(L2 + a);
        }
        short8 w[7];
#pragma unroll
        for (int t = 0; t < 7; t++) w[t] = *(const short8*)(W0 + woff[t] + ko);
        GPASS(w, f0);                       // w0*f0
        GPASS(w, f1);                       // w0*f1
        GPASS(w, f2);                       // w0*f2
#pragma unroll
        for (int t = 0; t < 7; t++) w[t] = *(const short8*)(W1 + woff[t] + ko);
        GPASS(w, f0);                       // w1*f0
        GPASS(w, f1);                       // w1*f1
#pragma unroll
        for (int t = 0; t < 7; t++) w[t] = *(const short8*)(W2 + woff[t] + ko);
        GPASS(w, f0);                       // w2*f0
    }
#undef GPASS

    __syncthreads();   // all limb reads complete before h limbs are overwritten

    // epilogue: gates; hold reconstructed exactly from limbs; new h split back.
#pragma unroll
    for (int t = 0; t < 7; t++) {
        const int ct = t * 4 + wave;        // 0..27
        const int d = ct * 4 + q;           // 0..111
        if (d < 100) {
            float4 b4 = *(const float4*)&bg[ct * 16 + 4 * q];
#pragma unroll
            for (int rf = 0; rf < 4; rf++) {
                int n = n0 + rf * 16 + m;
                size_t hb = (size_t)n * LROW + 112 + d;
                float hold = (limb2f(L2[hb]) + limb2f(L1[hb])) + limb2f(L0[hb]);
                float rp = acc[t][rf][0] + b4.x;
                float zp = acc[t][rf][1] + b4.y;
                float np = acc[t][rf][2] + b4.z;
                float hh = acc[t][rf][3] + b4.w;
                float rr = 1.f / (1.f + __expf(-rp));
                float zz = 1.f / (1.f + __expf(-zp));
                float nw = tanhf(np + rr * hh);
                float hnew = (1.f - zz) * nw + zz * hold;
                uint32 sh, sm, sl; split3(hnew, sh, sm, sl);
                L0[hb] = (ushort_t)sh; L1[hb] = (ushort_t)sm; L2[hb] = (ushort_t)sl;
            }
        }
    }
}

// ---------------------------------------------------------------- classifier
__global__ __launch_bounds__(256) void classifier(
    const ushort_t* __restrict__ L0, const ushort_t* __restrict__ L1,
    const ushort_t* __restrict__ L2, const float* __restrict__ W1,
    const float* __restrict__ b1, const float* __restrict__ W2,
    const float* __restrict__ b2, float* __restrict__ out) {
    __shared__ float Wc[3128];   // [3000,3128) zero pad: k in [100,104) rows
    __shared__ float bc[30];
    __shared__ float w2[30];
    int tid = threadIdx.x;
    for (int i = tid; i < 3128; i += 256) Wc[i] = (i < 3000) ? W1[i] : 0.f;
    if (tid < 30) { bc[tid] = b1[tid]; w2[tid] = W2[tid]; }
    __syncthreads();
    int n = blockIdx.x * 256 + tid;
    float a[30];
#pragma unroll
    for (int j = 0; j < 30; j++) a[j] = bc[j];
    const size_t base = (size_t)n * LROW + 112;
    for (int k8 = 0; k8 < 13; k8++) {     // k in [0,104); [100,104) limbs are 0
        int k0 = k8 * 8;
        union { short8 s; ushort_t u[8]; } h0, h1, h2;
        h0.s = *(const short8*)(L0 + base + k0);
        h1.s = *(const short8*)(L1 + base + k0);
        h2.s = *(const short8*)(L2 + base + k0);
#pragma unroll
        for (int jj = 0; jj < 8; jj++) {
            float hv = (limb2f(h2.u[jj]) + limb2f(h1.u[jj])) + limb2f(h0.u[jj]);
#pragma unroll
            for (int j = 0; j < 30; j++) a[j] = fmaf(hv, Wc[(k0 + jj) * 30 + j], a[j]);
        }
    }
    float s = b2[0];
#pragma unroll
    for (int j = 0; j < 30; j++) s = fmaf(fmaxf(a[j], 0.f), w2[j], s);
    out[n] = s;
}

// ---------------------------------------------------------------- launch
extern "C" void kernel_launch(void* const* d_in, const int* in_sizes, int n_in,
                              void* d_out, int out_size, void* d_ws, size_t ws_size,
                              hipStream_t stream) {
    const float* feat     = (const float*)d_in[0];
    const int*   er       = (const int*)d_in[1];
    const int*   ec       = (const int*)d_in[2];
    const float* init_W   = (const float*)d_in[3];
    const float* init_b   = (const float*)d_in[4];
    const float* fmsg_W1  = (const float*)d_in[5];
    const float* fmsg_b1  = (const float*)d_in[6];
    const float* fmsg_W2  = (const float*)d_in[7];
    const float* fmsg_b2  = (const float*)d_in[8];
    const float* bmsg_W1  = (const float*)d_in[9];
    const float* bmsg_b1  = (const float*)d_in[10];
    const float* bmsg_W2  = (const float*)d_in[11];
    const float* bmsg_b2  = (const float*)d_in[12];
    const float* fgru_Wih = (const float*)d_in[13];
    const float* fgru_Whh = (const float*)d_in[14];
    const float* fgru_bih = (const float*)d_in[15];
    const float* fgru_bhh = (const float*)d_in[16];
    const float* bgru_Wih = (const float*)d_in[17];
    const float* bgru_Whh = (const float*)d_in[18];
    const float* bgru_bih = (const float*)d_in[19];
    const float* bgru_bhh = (const float*)d_in[20];
    const float* cls_W1   = (const float*)d_in[21];
    const float* cls_b1   = (const float*)d_in[22];
    const float* cls_W2   = (const float*)d_in[23];
    const float* cls_b2   = (const float*)d_in[24];
    float* out = (float*)d_out;

    // Workspace budget (256 MiB hard limit):
    //   fm          52.43 MB
    //   limb planes 176.16 MB (3 x (Nn*224+64) shorts)
    //   weights     ~1.39 MB, biases ~5 KB
    //   CSR ints    ~6.29 MB
    //   total      ~236.3 MB  ✓
    float* ws = (float*)d_ws;
    size_t o = 0;
    float* fm = ws + o; o += (size_t)Nn * 100;            // [N][100] fp32

    const size_t PL = (size_t)Nn * LROW + 64;             // limb plane size (shorts)
    ushort_t* us = (ushort_t*)(ws + o);
    size_t uo = 0;
    ushort_t* L0 = us + uo; uo += PL;
    ushort_t* L1 = us + uo; uo += PL;
    ushort_t* L2 = us + uo; uo += PL;
    ushort_t* fWg0 = us + uo; uo += 448 * 224;
    ushort_t* fWg1 = us + uo; uo += 448 * 224;
    ushort_t* fWg2 = us + uo; uo += 448 * 224;
    ushort_t* bWg0 = us + uo; uo += 448 * 224;
    ushort_t* bWg1 = us + uo; uo += 448 * 224;
    ushort_t* bWg2 = us + uo; uo += 448 * 224;
    ushort_t* fA0 = us + uo; uo += 8192;
    ushort_t* fA1 = us + uo; uo += 8192;
    ushort_t* fA2 = us + uo; uo += 8192;
    ushort_t* bA0 = us + uo; uo += 8192;
    ushort_t* bA1 = us + uo; uo += 8192;
    ushort_t* bA2 = us + uo; uo += 8192;
    ushort_t* fB0 = us + uo; uo += 7168;
    ushort_t* fB1 = us + uo; uo += 7168;
    ushort_t* fB2 = us + uo; uo += 7168;
    ushort_t* bB0 = us + uo; uo += 7168;
    ushort_t* bB1 = us + uo; uo += 7168;
    ushort_t* bB2 = us + uo; uo += 7168;     // uo even
    o += uo / 2;

    float* bgf  = ws + o; o += 448;
    float* bgb  = ws + o; o += 448;
    float* b1pf = ws + o; o += 64;
    float* b1pb = ws + o; o += 64;
    float* b2pf = ws + o; o += 112;
    float* b2pb = ws + o; o += 112;

    int* iws   = (int*)(ws + o);
    int* ptr_f = iws;                       // N+1
    int* ptr_b = ptr_f + (Nn + 1);          // N+1
    int* cnt   = ptr_b + (Nn + 1);          // 2N
    int* cnt_f = cnt;
    int* cnt_b = cnt + Nn;
    int* src_f = cnt + 2 * (size_t)Nn;      // E
    int* src_b = src_f + Ee;                // E

    size_t need = o * sizeof(float) +
                  (size_t)(2 * (Nn + 1) + 2 * Nn + 2 * Ee) * sizeof(int);
    if (ws_size < need) {
        diag_kernel<<<(Nn + 255) / 256, 256, 0, stream>>>(out, (float)ws_size);
        return;
    }

    // zero limb planes once (pads [100,112) and [212,224) must stay 0; tail pad)
    {
        long n8 = (long)(3 * PL / 8);
        zero_short8<<<(int)((n8 + 255) / 256), 256, 0, stream>>>(L0, n8);
    }

    // CSR build
    zero_ints<<<(2 * Nn + 255) / 256, 256, 0, stream>>>(cnt, 2 * Nn);
    hist_kernel<<<Ee / 256, 256, 0, stream>>>(er, ec, cnt_f, cnt_b);
    scan2_kernel<<<2, 1024, 0, stream>>>(cnt_f, cnt_b, ptr_f, ptr_b, Nn);
    fill_kernel<<<Ee / 256, 256, 0, stream>>>(er, ec, ptr_f, ptr_b, src_f, src_b);

    // weight prep (split to 3 bf16 limbs)
    prep_gru_w<<<(448 * 224 + 255) / 256, 256, 0, stream>>>(
        fgru_Wih, fgru_Whh, fgru_bih, fgru_bhh, fWg0, fWg1, fWg2, bgf);
    prep_gru_w<<<(448 * 224 + 255) / 256, 256, 0, stream>>>(
        bgru_Wih, bgru_Whh, bgru_bih, bgru_bhh, bWg0, bWg1, bWg2, bgb);
    prep_msg_w<<<(15360 + 255) / 256, 256, 0, stream>>>(
        fmsg_W1, fmsg_b1, fmsg_W2, fmsg_b2, fA0, fA1, fA2, b1pf, fB0, fB1, fB2, b2pf);
    prep_msg_w<<<(15360 + 255) / 256, 256, 0, stream>>>(
        bmsg_W1, bmsg_b1, bmsg_W2, bmsg_b2, bA0, bA1, bA2, b1pb, bB0, bB1, bB2, b2pb);

    // h init (writes h limbs)
    init_h_kernel<<<(Nn * 100 + 255) / 256, 256, 0, stream>>>(
        feat, init_W, init_b, L0, L1, L2);

    const int gTile = Nn / 64;            // 2048 (msg)
    const int gGru  = Nn / 64;            // 2048 (gru, 64 rows/block)
    const int gGath = Nn * 25 / 256;      // 12800

    for (int rd = 0; rd < 20; rd++) {
        msg_mfma<<<gTile, 256, 0, stream>>>(L0, L1, L2,
            fA0, fA1, fA2, b1pf, fB0, fB1, fB2, b2pf, fm);
        gather4<<<gGath, 256, 0, stream>>>(fm, ptr_f, src_f, L0, L1, L2);
        gru_mfma<<<gGru, 256, 0, stream>>>(L0, L1, L2, fWg0, fWg1, fWg2, bgf);

        msg_mfma<<<gTile, 256, 0, stream>>>(L0, L1, L2,
            bA0, bA1, bA2, b1pb, bB0, bB1, bB2, b2pb, fm);
        gather4<<<gGath, 256, 0, stream>>>(fm, ptr_b, src_b, L0, L1, L2);
        gru_mfma<<<gGru, 256, 0, stream>>>(L0, L1, L2, bWg0, bWg1, bWg2, bgb);
    }

    classifier<<<Nn / 256, 256, 0, stream>>>(L0, L1, L2,
        cls_W1, cls_b1, cls_W2, cls_b2, out);
}

// Round 4
// 13848.067 us; speedup vs baseline: 1.1824x; 1.1824x over previous
//
#include <hip/hip_runtime.h>
#include <math.h>

#define Nn 131072
#define Ee 524288
#define LROW 224              // limb-plane row stride (shorts): msg[0,100) pad[100,112) h[112,212) pad[212,224)

typedef __attribute__((ext_vector_type(8))) short short8;
typedef __attribute__((ext_vector_type(4))) float f32x4;
typedef unsigned short ushort_t;
typedef unsigned int uint32;

__device__ __forceinline__ f32x4 mfma16(short8 a, short8 b, f32x4 c) {
    return __builtin_amdgcn_mfma_f32_16x16x32_bf16(a, b, c, 0, 0, 0);
}

__device__ __forceinline__ uint32 rne_bf16(float x) {
    uint32 u = __float_as_uint(x);
    return (u + 0x7FFFu + ((u >> 16) & 1u)) >> 16;
}

// fp32 -> 3 bf16 limbs (hi, mid, lo). For normal fp32 this decomposition is
// EXACT (8+8+8 mantissa bits; residual subtractions are Sterbenz-exact), and
// (l+m)+h reconstructs x exactly in fp32. The limb planes are therefore a
// lossless representation of the fp32 h state.
__device__ __forceinline__ void split3(float x, uint32& h, uint32& m, uint32& l) {
    h = rne_bf16(x);
    float hf = __uint_as_float(h << 16);
    float r1 = x - hf;
    m = rne_bf16(r1);
    float mf = __uint_as_float(m << 16);
    float r2 = r1 - mf;
    l = rne_bf16(r2);
}

__device__ __forceinline__ float limb2f(ushort_t u) {
    return __uint_as_float((uint32)u << 16);
}

// ---------------------------------------------------------------- diag / zero
__global__ void diag_kernel(float* out, float val) {
    int n = blockIdx.x * 256 + threadIdx.x;
    if (n < Nn) out[n] = (n == 0) ? val : 0.f;
}
__global__ void zero_ints(int* p, int n) {
    int i = blockIdx.x * 256 + threadIdx.x;
    if (i < n) p[i] = 0;
}
__global__ void zero_short8(ushort_t* p, long n8) {
    long i = (long)blockIdx.x * 256 + threadIdx.x;
    if (i < n8) {
        short8 zz = {0, 0, 0, 0, 0, 0, 0, 0};
        *(short8*)(p + i * 8) = zz;
    }
}

// ---------------------------------------------------------------- CSR build
__global__ void hist_kernel(const int* __restrict__ er, const int* __restrict__ ec,
                            int* __restrict__ cnt_f, int* __restrict__ cnt_b) {
    int e = blockIdx.x * 256 + threadIdx.x;
    atomicAdd(&cnt_f[er[e]], 1);
    atomicAdd(&cnt_b[ec[e]], 1);
}

// two independent scans in one launch (block 0: forward, block 1: backward)
__global__ __launch_bounds__(1024) void scan2_kernel(
    const int* __restrict__ cnt_f, const int* __restrict__ cnt_b,
    int* __restrict__ ptr_f, int* __restrict__ ptr_b, int n) {
    const int* cnt = blockIdx.x ? cnt_b : cnt_f;
    int* ptr = blockIdx.x ? ptr_b : ptr_f;
    __shared__ int sums[1024];
    int t = threadIdx.x;
    int chunk = n >> 10;
    int base = t * chunk;
    int s = 0;
    for (int i = 0; i < chunk; i++) s += cnt[base + i];
    sums[t] = s;
    __syncthreads();
    for (int off = 1; off < 1024; off <<= 1) {
        int v = (t >= off) ? sums[t - off] : 0;
        __syncthreads();
        sums[t] += v;
        __syncthreads();
    }
    int run = (t == 0) ? 0 : sums[t - 1];
    for (int i = 0; i < chunk; i++) { ptr[base + i] = run; run += cnt[base + i]; }
    if (t == 1023) ptr[n] = run;
}

// fill advances ptr in place; afterwards start(r) = (r ? ptr[r-1] : 0), end(r) = ptr[r]
__global__ void fill_kernel(const int* __restrict__ er, const int* __restrict__ ec,
                            int* __restrict__ ptr_f, int* __restrict__ ptr_b,
                            int* __restrict__ src_f, int* __restrict__ src_b) {
    int e = blockIdx.x * 256 + threadIdx.x;
    int r = er[e], c = ec[e];
    int p = atomicAdd(&ptr_f[r], 1); src_f[p] = c;
    int q = atomicAdd(&ptr_b[c], 1); src_b[q] = r;
}

// ---------------------------------------------------------------- weight prep
// GRU: Wt[c=4d+g][k], c<448 (28 tiles). k layout matches limb planes:
// k<100: Wih[., k], 112<=k<212: Whh[., k-112], else 0.
__global__ void prep_gru_w(const float* __restrict__ Wih, const float* __restrict__ Whh,
                           const float* __restrict__ bih, const float* __restrict__ bhh,
                           ushort_t* __restrict__ W0, ushort_t* __restrict__ W1,
                           ushort_t* __restrict__ W2, float* __restrict__ bg) {
    int gid = blockIdx.x * 256 + threadIdx.x;
    if (gid >= 448 * 224) return;
    int c = gid / 224, k = gid - c * 224;
    int d = c >> 2, g = c & 3;
    float w = 0.f;
    if (d < 100) {
        if (k < 100) {
            if (g == 0)      w = Wih[d * 100 + k];
            else if (g == 1) w = Wih[(100 + d) * 100 + k];
            else if (g == 2) w = Wih[(200 + d) * 100 + k];
        } else if (k >= 112 && k < 212) {
            int kk = k - 112;
            if (g == 0)      w = Whh[d * 100 + kk];
            else if (g == 1) w = Whh[(100 + d) * 100 + kk];
            else if (g == 3) w = Whh[(200 + d) * 100 + kk];
        }
    }
    uint32 h, m, l; split3(w, h, m, l);
    W0[gid] = (ushort_t)h; W1[gid] = (ushort_t)m; W2[gid] = (ushort_t)l;
    if (k == 0) {
        float b = 0.f;
        if (d < 100) {
            if (g == 0)      b = bih[d] + bhh[d];
            else if (g == 1) b = bih[100 + d] + bhh[100 + d];
            else if (g == 2) b = bih[200 + d];
            else             b = bhh[200 + d];
        }
        bg[c] = b;
    }
}

// msg MLP: W1t[c<64][k<128] (c=hidden col, k=h dim), W2t[c<112][k<64]
__global__ void prep_msg_w(const float* __restrict__ W1, const float* __restrict__ b1,
                           const float* __restrict__ W2, const float* __restrict__ b2,
                           ushort_t* __restrict__ A0, ushort_t* __restrict__ A1,
                           ushort_t* __restrict__ A2, float* __restrict__ b1p,
                           ushort_t* __restrict__ B0, ushort_t* __restrict__ B1,
                           ushort_t* __restrict__ B2, float* __restrict__ b2p) {
    int gid = blockIdx.x * 256 + threadIdx.x;
    if (gid < 8192) {
        int c = gid >> 7, k = gid & 127;
        float w = (c < 50 && k < 100) ? W1[k * 50 + c] : 0.f;
        uint32 h, m, l; split3(w, h, m, l);
        A0[gid] = (ushort_t)h; A1[gid] = (ushort_t)m; A2[gid] = (ushort_t)l;
        if (k == 0) b1p[c] = (c < 50) ? b1[c] : 0.f;
    } else if (gid < 8192 + 7168) {
        int t = gid - 8192;
        int c = t >> 6, k = t & 63;
        float w = (c < 100 && k < 50) ? W2[k * 100 + c] : 0.f;
        uint32 h, m, l; split3(w, h, m, l);
        B0[t] = (ushort_t)h; B1[t] = (ushort_t)m; B2[t] = (ushort_t)l;
        if (k == 0) b2p[c] = (c < 100) ? b2[c] : 0.f;
    }
}

// ---------------------------------------------------------------- init h
// h0 = feat @ init_W + b, split to limbs at k in [112,212) of the limb planes.
__global__ void init_h_kernel(const float* __restrict__ feat, const float* __restrict__ W,
                              const float* __restrict__ b,
                              ushort_t* __restrict__ L0, ushort_t* __restrict__ L1,
                              ushort_t* __restrict__ L2) {
    int gid = blockIdx.x * 256 + threadIdx.x;   // N*100
    if (gid >= Nn * 100) return;
    int n = gid / 100, d = gid - n * 100;
    float acc = b[d];
#pragma unroll
    for (int k = 0; k < 4; k++) acc += feat[n * 4 + k] * W[k * 100 + d];
    uint32 h, m, l; split3(acc, h, m, l);
    size_t a = (size_t)n * LROW + 112 + d;
    L0[a] = (ushort_t)h; L1[a] = (ushort_t)m; L2[a] = (ushort_t)l;
}

// ---------------------------------------------------------------- msg MLP (MFMA)
// fm = relu(h @ W1 + b1) @ W2 + b2 ; computed transposed: D[c][n].
// h inputs come straight from the limb planes (no fp32 load, no split3).
__global__ __launch_bounds__(256, 2) void msg_mfma(
    const ushort_t* __restrict__ L0, const ushort_t* __restrict__ L1,
    const ushort_t* __restrict__ L2,
    const ushort_t* __restrict__ A0, const ushort_t* __restrict__ A1,
    const ushort_t* __restrict__ A2, const float* __restrict__ b1p,
    const ushort_t* __restrict__ B0, const ushort_t* __restrict__ B1,
    const ushort_t* __restrict__ B2, const float* __restrict__ b2p,
    float* __restrict__ fm) {
    __shared__ ushort_t C1[3][64][72];
    const int tid = threadIdx.x;
    const int u = tid >> 6;          // wave = node tile
    const int lane = tid & 63;
    const int m = lane & 15, q = lane >> 4;
    const int n0 = blockIdx.x * 64;
    const int n = n0 + u * 16 + m;

    f32x4 z = {0.f, 0.f, 0.f, 0.f};
    f32x4 a1[4] = {z, z, z, z};

    const size_t hbase = (size_t)n * LROW + 112;
    for (int kc = 0; kc < 4; kc++) {
        int kb = kc * 32 + q * 8;
        // k in [kb, kb+8): real h for k<100, zeros for [100,112) pad;
        // kc==3 upper q over-reads into [224,240) = next row msg limbs /
        // tail pad — finite, and A-weights are zero for k>=100.
        short8 f0 = *(const short8*)(L0 + hbase + kb);
        short8 f1 = *(const short8*)(L1 + hbase + kb);
        short8 f2 = *(const short8*)(L2 + hbase + kb);
#pragma unroll
        for (int t = 0; t < 4; t++) {
            int off = (t * 16 + m) * 128 + kc * 32 + q * 8;
            short8 w0 = *(const short8*)(A0 + off);
            short8 w1 = *(const short8*)(A1 + off);
            short8 w2 = *(const short8*)(A2 + off);
            a1[t] = mfma16(w0, f0, a1[t]);
            a1[t] = mfma16(w0, f1, a1[t]);
            a1[t] = mfma16(w1, f0, a1[t]);
            a1[t] = mfma16(w0, f2, a1[t]);
            a1[t] = mfma16(w2, f0, a1[t]);
            a1[t] = mfma16(w1, f1, a1[t]);
        }
    }
    // epilogue 1: relu + split -> LDS
#pragma unroll
    for (int t = 0; t < 4; t++) {
        int c0 = t * 16 + 4 * q;
        float4 bb = *(const float4*)&b1p[c0];
        float v0 = fmaxf(a1[t][0] + bb.x, 0.f);
        float v1 = fmaxf(a1[t][1] + bb.y, 0.f);
        float v2 = fmaxf(a1[t][2] + bb.z, 0.f);
        float v3 = fmaxf(a1[t][3] + bb.w, 0.f);
        uint32 h0, m0, l0, h1, m1, l1, h2, m2, l2, h3, m3, l3;
        split3(v0, h0, m0, l0); split3(v1, h1, m1, l1);
        split3(v2, h2, m2, l2); split3(v3, h3, m3, l3);
        int nl = u * 16 + m;
        *(uint2*)&C1[0][nl][c0] = make_uint2(h0 | (h1 << 16), h2 | (h3 << 16));
        *(uint2*)&C1[1][nl][c0] = make_uint2(m0 | (m1 << 16), m2 | (m3 << 16));
        *(uint2*)&C1[2][nl][c0] = make_uint2(l0 | (l1 << 16), l2 | (l3 << 16));
    }
    __syncthreads();

    f32x4 a2[7] = {z, z, z, z, z, z, z};
    for (int kc = 0; kc < 2; kc++) {
        int nl = u * 16 + m;
        short8 c0f = *(const short8*)&C1[0][nl][kc * 32 + q * 8];
        short8 c1f = *(const short8*)&C1[1][nl][kc * 32 + q * 8];
        short8 c2f = *(const short8*)&C1[2][nl][kc * 32 + q * 8];
#pragma unroll
        for (int t = 0; t < 7; t++) {
            int off = (t * 16 + m) * 64 + kc * 32 + q * 8;
            short8 w0 = *(const short8*)(B0 + off);
            short8 w1 = *(const short8*)(B1 + off);
            short8 w2 = *(const short8*)(B2 + off);
            a2[t] = mfma16(w0, c0f, a2[t]);
            a2[t] = mfma16(w0, c1f, a2[t]);
            a2[t] = mfma16(w1, c0f, a2[t]);
            a2[t] = mfma16(w0, c2f, a2[t]);
            a2[t] = mfma16(w2, c0f, a2[t]);
            a2[t] = mfma16(w1, c1f, a2[t]);
        }
    }
#pragma unroll
    for (int t = 0; t < 7; t++) {
        int c0 = t * 16 + 4 * q;
        if (c0 < 100) {
            float4 bb = *(const float4*)&b2p[c0];
            float4 o;
            o.x = a2[t][0] + bb.x; o.y = a2[t][1] + bb.y;
            o.z = a2[t][2] + bb.z; o.w = a2[t][3] + bb.w;
            *(float4*)&fm[(size_t)n * 100 + c0] = o;
        }
    }
}

// ---------------------------------------------------------------- gather (CSR)
// Sums messages over incoming edges; stores the 3-limb split directly to the
// limb planes at k in [0,100) (gru's x = msg part).
__global__ void gather4(const float* __restrict__ fm, const int* __restrict__ ptr,
                        const int* __restrict__ idx,
                        ushort_t* __restrict__ L0, ushort_t* __restrict__ L1,
                        ushort_t* __restrict__ L2) {
    int gid = blockIdx.x * 256 + threadIdx.x;   // N*25
    int n = gid / 25, qq = (gid - n * 25) * 4;
    int s = (n == 0) ? 0 : ptr[n - 1];
    int e = ptr[n];
    float4 acc = {0.f, 0.f, 0.f, 0.f};
    for (int i = s; i < e; i++) {
        float4 v = *(const float4*)&fm[(size_t)idx[i] * 100 + qq];
        acc.x += v.x; acc.y += v.y; acc.z += v.z; acc.w += v.w;
    }
    uint32 h0, m0, l0, h1, m1, l1, h2, m2, l2, h3, m3, l3;
    split3(acc.x, h0, m0, l0); split3(acc.y, h1, m1, l1);
    split3(acc.z, h2, m2, l2); split3(acc.w, h3, m3, l3);
    size_t a = (size_t)n * LROW + qq;
    *(uint2*)&L0[a] = make_uint2(h0 | (h1 << 16), h2 | (h3 << 16));
    *(uint2*)&L1[a] = make_uint2(m0 | (m1 << 16), m2 | (m3 << 16));
    *(uint2*)&L2[a] = make_uint2(l0 | (l1 << 16), l2 | (l3 << 16));
}

// ---------------------------------------------------------------- GRU (MFMA) v8
// 128 rows/block, 512 threads = 8 waves (2 row-halves x 4 col-groups).
// - 4 col-waves of a row-half issue IDENTICAL limb loads (L1 dedup); the 2
//   row-halves share weights -> weight L2 traffic halved vs 64-row blocks.
// - Weights double-buffered (wA/wB): every w-set load is issued >=56 MFMA
//   before first use (incl. W0 of kc+1) -> no per-set vmcnt stall.
// - Epilogue via LDS transpose: vectorized limb reads (phase A) -> fp32 LDS,
//   gates in LDS (phase B), vectorized split+16B-store (phase C). This
//   replaces v7's scalar 2B scatter (the WRITE_SIZE 104MB / FETCH 134MB
//   amplification seen in rocprof).
__global__ __launch_bounds__(512, 2) void gru_mfma(
    ushort_t* __restrict__ L0, ushort_t* __restrict__ L1,
    ushort_t* __restrict__ L2,
    const ushort_t* __restrict__ W0, const ushort_t* __restrict__ W1,
    const ushort_t* __restrict__ W2, const float* __restrict__ bg) {
    __shared__ float SH[128][116];   // 59.4 KB; stride 116 -> 2-way banks (free)
    const int tid = threadIdx.x;
    const int wave = tid >> 6;
    const int rh = wave >> 2;        // row half (0/1)
    const int wc = wave & 3;         // col group
    const int lane = tid & 63;
    const int m = lane & 15, q = lane >> 4;
    const int n0 = blockIdx.x * 128;

    f32x4 z = {0.f, 0.f, 0.f, 0.f};
    f32x4 acc[7][4];
#pragma unroll
    for (int t = 0; t < 7; t++)
#pragma unroll
        for (int rf = 0; rf < 4; rf++) acc[t][rf] = z;

    int woff[7];
#pragma unroll
    for (int t = 0; t < 7; t++)
        woff[t] = ((t * 4 + wc) * 16 + m) * 224 + q * 8;

    const size_t abase = (size_t)(n0 + rh * 64 + m) * LROW + q * 8;

#define GP(Wreg, Fr)                                             \
    _Pragma("unroll")                                            \
    for (int t = 0; t < 7; t++) {                                \
        _Pragma("unroll")                                        \
        for (int rf = 0; rf < 4; rf++)                           \
            acc[t][rf] = mfma16(Wreg[t], Fr[rf], acc[t][rf]);    \
    }

    short8 wA[7], wB[7];
#pragma unroll
    for (int t = 0; t < 7; t++) wA[t] = *(const short8*)(W0 + woff[t]);  // W0 @ kc=0

#pragma unroll
    for (int kc = 0; kc < 7; kc++) {
        const int ko = kc * 32;
        short8 f0[4], f1[4], f2[4];
#pragma unroll
        for (int rf = 0; rf < 4; rf++)
            f0[rf] = *(const short8*)(L0 + abase + (size_t)rf * 16 * LROW + ko);
#pragma unroll
        for (int rf = 0; rf < 4; rf++)
            f1[rf] = *(const short8*)(L1 + abase + (size_t)rf * 16 * LROW + ko);
#pragma unroll
        for (int rf = 0; rf < 4; rf++)
            f2[rf] = *(const short8*)(L2 + abase + (size_t)rf * 16 * LROW + ko);

        if ((kc & 1) == 0) {           // W0 currently in wA
#pragma unroll
            for (int t = 0; t < 7; t++) wB[t] = *(const short8*)(W1 + woff[t] + ko);
            GP(wA, f0); GP(wA, f1); GP(wA, f2);          // W0 products
#pragma unroll
            for (int t = 0; t < 7; t++) wA[t] = *(const short8*)(W2 + woff[t] + ko);
            GP(wB, f0); GP(wB, f1);                      // W1 products
            if (kc < 6) {
#pragma unroll
                for (int t = 0; t < 7; t++) wB[t] = *(const short8*)(W0 + woff[t] + ko + 32);
            }
            GP(wA, f0);                                  // W2 product
        } else {                        // W0 currently in wB
#pragma unroll
            for (int t = 0; t < 7; t++) wA[t] = *(const short8*)(W1 + woff[t] + ko);
            GP(wB, f0); GP(wB, f1); GP(wB, f2);          // W0 products
#pragma unroll
            for (int t = 0; t < 7; t++) wB[t] = *(const short8*)(W2 + woff[t] + ko);
            GP(wA, f0); GP(wA, f1);                      // W1 products
            if (kc < 6) {
#pragma unroll
                for (int t = 0; t < 7; t++) wA[t] = *(const short8*)(W0 + woff[t] + ko + 32);
            }
            GP(wB, f0);                                  // W2 product
        }
    }
#undef GP

    // ---- epilogue phase A: cooperative hold reconstruction -> LDS fp32
#pragma unroll
    for (int p = 0; p < 4; p++) {
        int idx = tid + p * 512;          // 2048 slots: 128 rows x 16 chunks
        int row = idx >> 4, c = idx & 15;
        if (c < 13) {                     // cols [0,104): h[0,100) + zero pad
            size_t g = (size_t)(n0 + row) * LROW + 112 + c * 8;
            union { short8 s; ushort_t u[8]; } a0, a1, a2;
            a0.s = *(const short8*)(L0 + g);
            a1.s = *(const short8*)(L1 + g);
            a2.s = *(const short8*)(L2 + g);
#pragma unroll
            for (int j = 0; j < 8; j++)
                SH[row][c * 8 + j] =
                    (limb2f(a2.u[j]) + limb2f(a1.u[j])) + limb2f(a0.u[j]);
        }
    }
    __syncthreads();

    // ---- epilogue phase B: gates (each (row,d) owned by exactly one thread)
#pragma unroll
    for (int t = 0; t < 7; t++) {
        const int ct = t * 4 + wc;          // 0..27
        const int d = ct * 4 + q;           // 0..111
        if (d < 100) {
            float4 b4 = *(const float4*)&bg[ct * 16 + 4 * q];
#pragma unroll
            for (int rf = 0; rf < 4; rf++) {
                int row = rh * 64 + rf * 16 + m;
                float hold = SH[row][d];
                float rp = acc[t][rf][0] + b4.x;
                float zp = acc[t][rf][1] + b4.y;
                float np = acc[t][rf][2] + b4.z;
                float hh = acc[t][rf][3] + b4.w;
                float rr = 1.f / (1.f + __expf(-rp));
                float zz = 1.f / (1.f + __expf(-zp));
                float nw = tanhf(np + rr * hh);
                SH[row][d] = (1.f - zz) * nw + zz * hold;
            }
        }
    }
    __syncthreads();

    // ---- epilogue phase C: cooperative split + vectorized 16B limb stores
#pragma unroll
    for (int p = 0; p < 4; p++) {
        int idx = tid + p * 512;
        int row = idx >> 4, c = idx & 15;
        if (c < 13) {
            size_t g = (size_t)(n0 + row) * LROW + 112 + c * 8;
            union { short8 s; uint32 u4[4]; } o0, o1, o2;
#pragma unroll
            for (int jj = 0; jj < 4; jj++) {
                float ea = SH[row][c * 8 + 2 * jj];
                float eb = SH[row][c * 8 + 2 * jj + 1];
                uint32 ha, ma, la, hb, mb, lb;
                split3(ea, ha, ma, la);
                split3(eb, hb, mb, lb);
                o0.u4[jj] = ha | (hb << 16);
                o1.u4[jj] = ma | (mb << 16);
                o2.u4[jj] = la | (lb << 16);
            }
            *(short8*)(L0 + g) = o0.s;
            *(short8*)(L1 + g) = o1.s;
            *(short8*)(L2 + g) = o2.s;
        }
    }
}

// ---------------------------------------------------------------- classifier
__global__ __launch_bounds__(256) void classifier(
    const ushort_t* __restrict__ L0, const ushort_t* __restrict__ L1,
    const ushort_t* __restrict__ L2, const float* __restrict__ W1,
    const float* __restrict__ b1, const float* __restrict__ W2,
    const float* __restrict__ b2, float* __restrict__ out) {
    __shared__ float Wc[3128];   // [3000,3128) zero pad: k in [100,104) rows
    __shared__ float bc[30];
    __shared__ float w2[30];
    int tid = threadIdx.x;
    for (int i = tid; i < 3128; i += 256) Wc[i] = (i < 3000) ? W1[i] : 0.f;
    if (tid < 30) { bc[tid] = b1[tid]; w2[tid] = W2[tid]; }
    __syncthreads();
    int n = blockIdx.x * 256 + tid;
    float a[30];
#pragma unroll
    for (int j = 0; j < 30; j++) a[j] = bc[j];
    const size_t base = (size_t)n * LROW + 112;
    for (int k8 = 0; k8 < 13; k8++) {     // k in [0,104); [100,104) limbs are 0
        int k0 = k8 * 8;
        union { short8 s; ushort_t u[8]; } h0, h1, h2;
        h0.s = *(const short8*)(L0 + base + k0);
        h1.s = *(const short8*)(L1 + base + k0);
        h2.s = *(const short8*)(L2 + base + k0);
#pragma unroll
        for (int jj = 0; jj < 8; jj++) {
            float hv = (limb2f(h2.u[jj]) + limb2f(h1.u[jj])) + limb2f(h0.u[jj]);
#pragma unroll
            for (int j = 0; j < 30; j++) a[j] = fmaf(hv, Wc[(k0 + jj) * 30 + j], a[j]);
        }
    }
    float s = b2[0];
#pragma unroll
    for (int j = 0; j < 30; j++) s = fmaf(fmaxf(a[j], 0.f), w2[j], s);
    out[n] = s;
}

// ---------------------------------------------------------------- launch
extern "C" void kernel_launch(void* const* d_in, const int* in_sizes, int n_in,
                              void* d_out, int out_size, void* d_ws, size_t ws_size,
                              hipStream_t stream) {
    const float* feat     = (const float*)d_in[0];
    const int*   er       = (const int*)d_in[1];
    const int*   ec       = (const int*)d_in[2];
    const float* init_W   = (const float*)d_in[3];
    const float* init_b   = (const float*)d_in[4];
    const float* fmsg_W1  = (const float*)d_in[5];
    const float* fmsg_b1  = (const float*)d_in[6];
    const float* fmsg_W2  = (const float*)d_in[7];
    const float* fmsg_b2  = (const float*)d_in[8];
    const float* bmsg_W1  = (const float*)d_in[9];
    const float* bmsg_b1  = (const float*)d_in[10];
    const float* bmsg_W2  = (const float*)d_in[11];
    const float* bmsg_b2  = (const float*)d_in[12];
    const float* fgru_Wih = (const float*)d_in[13];
    const float* fgru_Whh = (const float*)d_in[14];
    const float* fgru_bih = (const float*)d_in[15];
    const float* fgru_bhh = (const float*)d_in[16];
    const float* bgru_Wih = (const float*)d_in[17];
    const float* bgru_Whh = (const float*)d_in[18];
    const float* bgru_bih = (const float*)d_in[19];
    const float* bgru_bhh = (const float*)d_in[20];
    const float* cls_W1   = (const float*)d_in[21];
    const float* cls_b1   = (const float*)d_in[22];
    const float* cls_W2   = (const float*)d_in[23];
    const float* cls_b2   = (const float*)d_in[24];
    float* out = (float*)d_out;

    // Workspace budget (256 MiB hard limit):
    //   fm          52.43 MB
    //   limb planes 176.16 MB (3 x (Nn*224+64) shorts)
    //   weights     ~1.39 MB, biases ~5 KB
    //   CSR ints    ~6.29 MB
    //   total      ~236.3 MB  OK
    float* ws = (float*)d_ws;
    size_t o = 0;
    float* fm = ws + o; o += (size_t)Nn * 100;            // [N][100] fp32

    const size_t PL = (size_t)Nn * LROW + 64;             // limb plane size (shorts)
    ushort_t* us = (ushort_t*)(ws + o);
    size_t uo = 0;
    ushort_t* L0 = us + uo; uo += PL;
    ushort_t* L1 = us + uo; uo += PL;
    ushort_t* L2 = us + uo; uo += PL;
    ushort_t* fWg0 = us + uo; uo += 448 * 224;
    ushort_t* fWg1 = us + uo; uo += 448 * 224;
    ushort_t* fWg2 = us + uo; uo += 448 * 224;
    ushort_t* bWg0 = us + uo; uo += 448 * 224;
    ushort_t* bWg1 = us + uo; uo += 448 * 224;
    ushort_t* bWg2 = us + uo; uo += 448 * 224;
    ushort_t* fA0 = us + uo; uo += 8192;
    ushort_t* fA1 = us + uo; uo += 8192;
    ushort_t* fA2 = us + uo; uo += 8192;
    ushort_t* bA0 = us + uo; uo += 8192;
    ushort_t* bA1 = us + uo; uo += 8192;
    ushort_t* bA2 = us + uo; uo += 8192;
    ushort_t* fB0 = us + uo; uo += 7168;
    ushort_t* fB1 = us + uo; uo += 7168;
    ushort_t* fB2 = us + uo; uo += 7168;
    ushort_t* bB0 = us + uo; uo += 7168;
    ushort_t* bB1 = us + uo; uo += 7168;
    ushort_t* bB2 = us + uo; uo += 7168;     // uo even
    o += uo / 2;

    float* bgf  = ws + o; o += 448;
    float* bgb  = ws + o; o += 448;
    float* b1pf = ws + o; o += 64;
    float* b1pb = ws + o; o += 64;
    float* b2pf = ws + o; o += 112;
    float* b2pb = ws + o; o += 112;

    int* iws   = (int*)(ws + o);
    int* ptr_f = iws;                       // N+1
    int* ptr_b = ptr_f + (Nn + 1);          // N+1
    int* cnt   = ptr_b + (Nn + 1);          // 2N
    int* cnt_f = cnt;
    int* cnt_b = cnt + Nn;
    int* src_f = cnt + 2 * (size_t)Nn;      // E
    int* src_b = src_f + Ee;                // E

    size_t need = o * sizeof(float) +
                  (size_t)(2 * (Nn + 1) + 2 * Nn + 2 * Ee) * sizeof(int);
    if (ws_size < need) {
        diag_kernel<<<(Nn + 255) / 256, 256, 0, stream>>>(out, (float)ws_size);
        return;
    }

    // zero limb planes once (pads [100,112) and [212,224) must stay 0; tail pad)
    {
        long n8 = (long)(3 * PL / 8);
        zero_short8<<<(int)((n8 + 255) / 256), 256, 0, stream>>>(L0, n8);
    }

    // CSR build
    zero_ints<<<(2 * Nn + 255) / 256, 256, 0, stream>>>(cnt, 2 * Nn);
    hist_kernel<<<Ee / 256, 256, 0, stream>>>(er, ec, cnt_f, cnt_b);
    scan2_kernel<<<2, 1024, 0, stream>>>(cnt_f, cnt_b, ptr_f, ptr_b, Nn);
    fill_kernel<<<Ee / 256, 256, 0, stream>>>(er, ec, ptr_f, ptr_b, src_f, src_b);

    // weight prep (split to 3 bf16 limbs)
    prep_gru_w<<<(448 * 224 + 255) / 256, 256, 0, stream>>>(
        fgru_Wih, fgru_Whh, fgru_bih, fgru_bhh, fWg0, fWg1, fWg2, bgf);
    prep_gru_w<<<(448 * 224 + 255) / 256, 256, 0, stream>>>(
        bgru_Wih, bgru_Whh, bgru_bih, bgru_bhh, bWg0, bWg1, bWg2, bgb);
    prep_msg_w<<<(15360 + 255) / 256, 256, 0, stream>>>(
        fmsg_W1, fmsg_b1, fmsg_W2, fmsg_b2, fA0, fA1, fA2, b1pf, fB0, fB1, fB2, b2pf);
    prep_msg_w<<<(15360 + 255) / 256, 256, 0, stream>>>(
        bmsg_W1, bmsg_b1, bmsg_W2, bmsg_b2, bA0, bA1, bA2, b1pb, bB0, bB1, bB2, b2pb);

    // h init (writes h limbs)
    init_h_kernel<<<(Nn * 100 + 255) / 256, 256, 0, stream>>>(
        feat, init_W, init_b, L0, L1, L2);

    const int gTile = Nn / 64;            // 2048 (msg)
    const int gGru  = Nn / 128;           // 1024 (gru, 128 rows/block, 512 thr)
    const int gGath = Nn * 25 / 256;      // 12800

    for (int rd = 0; rd < 20; rd++) {
        msg_mfma<<<gTile, 256, 0, stream>>>(L0, L1, L2,
            fA0, fA1, fA2, b1pf, fB0, fB1, fB2, b2pf, fm);
        gather4<<<gGath, 256, 0, stream>>>(fm, ptr_f, src_f, L0, L1, L2);
        gru_mfma<<<gGru, 512, 0, stream>>>(L0, L1, L2, fWg0, fWg1, fWg2, bgf);

        msg_mfma<<<gTile, 256, 0, stream>>>(L0, L1, L2,
            bA0, bA1, bA2, b1pb, bB0, bB1, bB2, b2pb, fm);
        gather4<<<gGath, 256, 0, stream>>>(fm, ptr_b, src_b, L0, L1, L2);
        gru_mfma<<<gGru, 512, 0, stream>>>(L0, L1, L2, bWg0, bWg1, bWg2, bgb);
    }

    classifier<<<Nn / 256, 256, 0, stream>>>(L0, L1, L2,
        cls_W1, cls_b1, cls_W2, cls_b2, out);
}

// Round 5
// 13380.208 us; speedup vs baseline: 1.2237x; 1.0350x over previous
//
#include <hip/hip_runtime.h>
#include <math.h>

#define Nn 131072
#define Ee 524288
#define LROW 224              // limb-plane row stride (shorts): msg[0,100) pad[100,112) h[112,212) pad[212,224)

typedef __attribute__((ext_vector_type(8))) short short8;
typedef __attribute__((ext_vector_type(4))) float f32x4;
typedef unsigned short ushort_t;
typedef unsigned int uint32;

__device__ __forceinline__ f32x4 mfma16(short8 a, short8 b, f32x4 c) {
    return __builtin_amdgcn_mfma_f32_16x16x32_bf16(a, b, c, 0, 0, 0);
}

__device__ __forceinline__ uint32 rne_bf16(float x) {
    uint32 u = __float_as_uint(x);
    return (u + 0x7FFFu + ((u >> 16) & 1u)) >> 16;
}

// fp32 -> 3 bf16 limbs (hi, mid, lo). For normal fp32 this decomposition is
// EXACT (8+8+8 mantissa bits; residual subtractions are Sterbenz-exact), and
// (l+m)+h reconstructs x exactly in fp32.
__device__ __forceinline__ void split3(float x, uint32& h, uint32& m, uint32& l) {
    h = rne_bf16(x);
    float hf = __uint_as_float(h << 16);
    float r1 = x - hf;
    m = rne_bf16(r1);
    float mf = __uint_as_float(m << 16);
    float r2 = r1 - mf;
    l = rne_bf16(r2);
}

__device__ __forceinline__ float limb2f(ushort_t u) {
    return __uint_as_float((uint32)u << 16);
}

// async global->LDS, 16B per lane. LDS dest is wave-uniform base + lane*16
// (m104); global src is per-lane.
__device__ __forceinline__ void gl16(const ushort_t* g, ushort_t* l) {
    __builtin_amdgcn_global_load_lds(
        (const __attribute__((address_space(1))) uint32*)g,
        (__attribute__((address_space(3))) uint32*)l, 16, 0, 0);
}

// ---------------------------------------------------------------- diag / zero
__global__ void diag_kernel(float* out, float val) {
    int n = blockIdx.x * 256 + threadIdx.x;
    if (n < Nn) out[n] = (n == 0) ? val : 0.f;
}
__global__ void zero_ints(int* p, int n) {
    int i = blockIdx.x * 256 + threadIdx.x;
    if (i < n) p[i] = 0;
}
__global__ void zero_short8(ushort_t* p, long n8) {
    long i = (long)blockIdx.x * 256 + threadIdx.x;
    if (i < n8) {
        short8 zz = {0, 0, 0, 0, 0, 0, 0, 0};
        *(short8*)(p + i * 8) = zz;
    }
}

// ---------------------------------------------------------------- CSR build
__global__ void hist_kernel(const int* __restrict__ er, const int* __restrict__ ec,
                            int* __restrict__ cnt_f, int* __restrict__ cnt_b) {
    int e = blockIdx.x * 256 + threadIdx.x;
    atomicAdd(&cnt_f[er[e]], 1);
    atomicAdd(&cnt_b[ec[e]], 1);
}

// two independent scans in one launch (block 0: forward, block 1: backward)
__global__ __launch_bounds__(1024) void scan2_kernel(
    const int* __restrict__ cnt_f, const int* __restrict__ cnt_b,
    int* __restrict__ ptr_f, int* __restrict__ ptr_b, int n) {
    const int* cnt = blockIdx.x ? cnt_b : cnt_f;
    int* ptr = blockIdx.x ? ptr_b : ptr_f;
    __shared__ int sums[1024];
    int t = threadIdx.x;
    int chunk = n >> 10;
    int base = t * chunk;
    int s = 0;
    for (int i = 0; i < chunk; i++) s += cnt[base + i];
    sums[t] = s;
    __syncthreads();
    for (int off = 1; off < 1024; off <<= 1) {
        int v = (t >= off) ? sums[t - off] : 0;
        __syncthreads();
        sums[t] += v;
        __syncthreads();
    }
    int run = (t == 0) ? 0 : sums[t - 1];
    for (int i = 0; i < chunk; i++) { ptr[base + i] = run; run += cnt[base + i]; }
    if (t == 1023) ptr[n] = run;
}

// fill advances ptr in place; afterwards start(r) = (r ? ptr[r-1] : 0), end(r) = ptr[r]
__global__ void fill_kernel(const int* __restrict__ er, const int* __restrict__ ec,
                            int* __restrict__ ptr_f, int* __restrict__ ptr_b,
                            int* __restrict__ src_f, int* __restrict__ src_b) {
    int e = blockIdx.x * 256 + threadIdx.x;
    int r = er[e], c = ec[e];
    int p = atomicAdd(&ptr_f[r], 1); src_f[p] = c;
    int q = atomicAdd(&ptr_b[c], 1); src_b[q] = r;
}

// ---------------------------------------------------------------- weight prep
// GRU: Wt[c=4d+g][k], c<448 (28 tiles). k layout matches limb planes:
// k<100: Wih[., k], 112<=k<212: Whh[., k-112], else 0.
__global__ void prep_gru_w(const float* __restrict__ Wih, const float* __restrict__ Whh,
                           const float* __restrict__ bih, const float* __restrict__ bhh,
                           ushort_t* __restrict__ W0, ushort_t* __restrict__ W1,
                           ushort_t* __restrict__ W2, float* __restrict__ bg) {
    int gid = blockIdx.x * 256 + threadIdx.x;
    if (gid >= 448 * 224) return;
    int c = gid / 224, k = gid - c * 224;
    int d = c >> 2, g = c & 3;
    float w = 0.f;
    if (d < 100) {
        if (k < 100) {
            if (g == 0)      w = Wih[d * 100 + k];
            else if (g == 1) w = Wih[(100 + d) * 100 + k];
            else if (g == 2) w = Wih[(200 + d) * 100 + k];
        } else if (k >= 112 && k < 212) {
            int kk = k - 112;
            if (g == 0)      w = Whh[d * 100 + kk];
            else if (g == 1) w = Whh[(100 + d) * 100 + kk];
            else if (g == 3) w = Whh[(200 + d) * 100 + kk];
        }
    }
    uint32 h, m, l; split3(w, h, m, l);
    W0[gid] = (ushort_t)h; W1[gid] = (ushort_t)m; W2[gid] = (ushort_t)l;
    if (k == 0) {
        float b = 0.f;
        if (d < 100) {
            if (g == 0)      b = bih[d] + bhh[d];
            else if (g == 1) b = bih[100 + d] + bhh[100 + d];
            else if (g == 2) b = bih[200 + d];
            else             b = bhh[200 + d];
        }
        bg[c] = b;
    }
}

// msg MLP: W1t[c<64][k<128] (c=hidden col, k=h dim), W2t[c<112][k<64]
__global__ void prep_msg_w(const float* __restrict__ W1, const float* __restrict__ b1,
                           const float* __restrict__ W2, const float* __restrict__ b2,
                           ushort_t* __restrict__ A0, ushort_t* __restrict__ A1,
                           ushort_t* __restrict__ A2, float* __restrict__ b1p,
                           ushort_t* __restrict__ B0, ushort_t* __restrict__ B1,
                           ushort_t* __restrict__ B2, float* __restrict__ b2p) {
    int gid = blockIdx.x * 256 + threadIdx.x;
    if (gid < 8192) {
        int c = gid >> 7, k = gid & 127;
        float w = (c < 50 && k < 100) ? W1[k * 50 + c] : 0.f;
        uint32 h, m, l; split3(w, h, m, l);
        A0[gid] = (ushort_t)h; A1[gid] = (ushort_t)m; A2[gid] = (ushort_t)l;
        if (k == 0) b1p[c] = (c < 50) ? b1[c] : 0.f;
    } else if (gid < 8192 + 7168) {
        int t = gid - 8192;
        int c = t >> 6, k = t & 63;
        float w = (c < 100 && k < 50) ? W2[k * 100 + c] : 0.f;
        uint32 h, m, l; split3(w, h, m, l);
        B0[t] = (ushort_t)h; B1[t] = (ushort_t)m; B2[t] = (ushort_t)l;
        if (k == 0) b2p[c] = (c < 100) ? b2[c] : 0.f;
    }
}

// ---------------------------------------------------------------- init h
// h0 = feat @ init_W + b, split to limbs at k in [112,212) of the limb planes.
__global__ void init_h_kernel(const float* __restrict__ feat, const float* __restrict__ W,
                              const float* __restrict__ b,
                              ushort_t* __restrict__ L0, ushort_t* __restrict__ L1,
                              ushort_t* __restrict__ L2) {
    int gid = blockIdx.x * 256 + threadIdx.x;   // N*100
    if (gid >= Nn * 100) return;
    int n = gid / 100, d = gid - n * 100;
    float acc = b[d];
#pragma unroll
    for (int k = 0; k < 4; k++) acc += feat[n * 4 + k] * W[k * 100 + d];
    uint32 h, m, l; split3(acc, h, m, l);
    size_t a = (size_t)n * LROW + 112 + d;
    L0[a] = (ushort_t)h; L1[a] = (ushort_t)m; L2[a] = (ushort_t)l;
}

// ---------------------------------------------------------------- msg MLP (MFMA)
// fm = relu(h @ W1 + b1) @ W2 + b2 ; computed transposed: D[c][n].
// h inputs come straight from the limb planes (no fp32 load, no split3).
__global__ __launch_bounds__(256, 2) void msg_mfma(
    const ushort_t* __restrict__ L0, const ushort_t* __restrict__ L1,
    const ushort_t* __restrict__ L2,
    const ushort_t* __restrict__ A0, const ushort_t* __restrict__ A1,
    const ushort_t* __restrict__ A2, const float* __restrict__ b1p,
    const ushort_t* __restrict__ B0, const ushort_t* __restrict__ B1,
    const ushort_t* __restrict__ B2, const float* __restrict__ b2p,
    float* __restrict__ fm) {
    __shared__ ushort_t C1[3][64][72];
    const int tid = threadIdx.x;
    const int u = tid >> 6;          // wave = node tile
    const int lane = tid & 63;
    const int m = lane & 15, q = lane >> 4;
    const int n0 = blockIdx.x * 64;
    const int n = n0 + u * 16 + m;

    f32x4 z = {0.f, 0.f, 0.f, 0.f};
    f32x4 a1[4] = {z, z, z, z};

    const size_t hbase = (size_t)n * LROW + 112;
    for (int kc = 0; kc < 4; kc++) {
        int kb = kc * 32 + q * 8;
        // k in [kb, kb+8): real h for k<100, zeros for [100,112) pad;
        // kc==3 upper q over-reads into [224,240) = next row msg limbs /
        // tail pad — finite, and A-weights are zero for k>=100.
        short8 f0 = *(const short8*)(L0 + hbase + kb);
        short8 f1 = *(const short8*)(L1 + hbase + kb);
        short8 f2 = *(const short8*)(L2 + hbase + kb);
#pragma unroll
        for (int t = 0; t < 4; t++) {
            int off = (t * 16 + m) * 128 + kc * 32 + q * 8;
            short8 w0 = *(const short8*)(A0 + off);
            short8 w1 = *(const short8*)(A1 + off);
            short8 w2 = *(const short8*)(A2 + off);
            a1[t] = mfma16(w0, f0, a1[t]);
            a1[t] = mfma16(w0, f1, a1[t]);
            a1[t] = mfma16(w1, f0, a1[t]);
            a1[t] = mfma16(w0, f2, a1[t]);
            a1[t] = mfma16(w2, f0, a1[t]);
            a1[t] = mfma16(w1, f1, a1[t]);
        }
    }
    // epilogue 1: relu + split -> LDS
#pragma unroll
    for (int t = 0; t < 4; t++) {
        int c0 = t * 16 + 4 * q;
        float4 bb = *(const float4*)&b1p[c0];
        float v0 = fmaxf(a1[t][0] + bb.x, 0.f);
        float v1 = fmaxf(a1[t][1] + bb.y, 0.f);
        float v2 = fmaxf(a1[t][2] + bb.z, 0.f);
        float v3 = fmaxf(a1[t][3] + bb.w, 0.f);
        uint32 h0, m0, l0, h1, m1, l1, h2, m2, l2, h3, m3, l3;
        split3(v0, h0, m0, l0); split3(v1, h1, m1, l1);
        split3(v2, h2, m2, l2); split3(v3, h3, m3, l3);
        int nl = u * 16 + m;
        *(uint2*)&C1[0][nl][c0] = make_uint2(h0 | (h1 << 16), h2 | (h3 << 16));
        *(uint2*)&C1[1][nl][c0] = make_uint2(m0 | (m1 << 16), m2 | (m3 << 16));
        *(uint2*)&C1[2][nl][c0] = make_uint2(l0 | (l1 << 16), l2 | (l3 << 16));
    }
    __syncthreads();

    f32x4 a2[7] = {z, z, z, z, z, z, z};
    for (int kc = 0; kc < 2; kc++) {
        int nl = u * 16 + m;
        short8 c0f = *(const short8*)&C1[0][nl][kc * 32 + q * 8];
        short8 c1f = *(const short8*)&C1[1][nl][kc * 32 + q * 8];
        short8 c2f = *(const short8*)&C1[2][nl][kc * 32 + q * 8];
#pragma unroll
        for (int t = 0; t < 7; t++) {
            int off = (t * 16 + m) * 64 + kc * 32 + q * 8;
            short8 w0 = *(const short8*)(B0 + off);
            short8 w1 = *(const short8*)(B1 + off);
            short8 w2 = *(const short8*)(B2 + off);
            a2[t] = mfma16(w0, c0f, a2[t]);
            a2[t] = mfma16(w0, c1f, a2[t]);
            a2[t] = mfma16(w1, c0f, a2[t]);
            a2[t] = mfma16(w0, c2f, a2[t]);
            a2[t] = mfma16(w2, c0f, a2[t]);
            a2[t] = mfma16(w1, c1f, a2[t]);
        }
    }
#pragma unroll
    for (int t = 0; t < 7; t++) {
        int c0 = t * 16 + 4 * q;
        if (c0 < 100) {
            float4 bb = *(const float4*)&b2p[c0];
            float4 o;
            o.x = a2[t][0] + bb.x; o.y = a2[t][1] + bb.y;
            o.z = a2[t][2] + bb.z; o.w = a2[t][3] + bb.w;
            *(float4*)&fm[(size_t)n * 100 + c0] = o;
        }
    }
}

// ---------------------------------------------------------------- gather (CSR)
// Sums messages over incoming edges; stores the 3-limb split directly to the
// limb planes at k in [0,100) (gru's x = msg part).
__global__ void gather4(const float* __restrict__ fm, const int* __restrict__ ptr,
                        const int* __restrict__ idx,
                        ushort_t* __restrict__ L0, ushort_t* __restrict__ L1,
                        ushort_t* __restrict__ L2) {
    int gid = blockIdx.x * 256 + threadIdx.x;   // N*25
    int n = gid / 25, qq = (gid - n * 25) * 4;
    int s = (n == 0) ? 0 : ptr[n - 1];
    int e = ptr[n];
    float4 acc = {0.f, 0.f, 0.f, 0.f};
    for (int i = s; i < e; i++) {
        float4 v = *(const float4*)&fm[(size_t)idx[i] * 100 + qq];
        acc.x += v.x; acc.y += v.y; acc.z += v.z; acc.w += v.w;
    }
    uint32 h0, m0, l0, h1, m1, l1, h2, m2, l2, h3, m3, l3;
    split3(acc.x, h0, m0, l0); split3(acc.y, h1, m1, l1);
    split3(acc.z, h2, m2, l2); split3(acc.w, h3, m3, l3);
    size_t a = (size_t)n * LROW + qq;
    *(uint2*)&L0[a] = make_uint2(h0 | (h1 << 16), h2 | (h3 << 16));
    *(uint2*)&L1[a] = make_uint2(m0 | (m1 << 16), m2 | (m3 << 16));
    *(uint2*)&L2[a] = make_uint2(l0 | (l1 << 16), l2 | (l3 << 16));
}

// ---------------------------------------------------------------- GRU (MFMA) v9
// 64 rows/block, 256 threads (4 col-waves) -> 2 independent blocks/CU
// (VGPR ~135 + 112 acc <= 256 unified), decorrelating stalls.
// Limb fragments staged global->LDS via global_load_lds (16B/lane), double
// buffered, issued ONE FULL kc (~815 cyc of MFMA) before consumption: the
// vmcnt drain at the per-kc __syncthreads is then nearly free, and the
// per-kc L3/HBM latency stall of v8's direct loads disappears.
// Source-XOR swizzle (chunk ^= (row>>1)&3) with linear LDS dest + same
// swizzle on ds_read: read conflicts ~2-way (free). Weights stay register
// double-buffered from L2.
typedef union {
    ushort_t lbuf[2][3][64][32];   // [buf][plane][row][k-chunk]  24 KB
    float    sh[64][116];          // epilogue scratch            29.7 KB
} GruShm;

__global__ __launch_bounds__(256, 2) void gru_mfma(
    ushort_t* __restrict__ L0, ushort_t* __restrict__ L1,
    ushort_t* __restrict__ L2,
    const ushort_t* __restrict__ W0, const ushort_t* __restrict__ W1,
    const ushort_t* __restrict__ W2, const float* __restrict__ bg) {
    __shared__ GruShm U;
    const int tid = threadIdx.x;
    const int wave = tid >> 6;       // col group 0..3
    const int lane = tid & 63;
    const int m = lane & 15, q = lane >> 4;
    const int n0 = blockIdx.x * 64;

    // staging geometry: wave w stages rows [16w,16w+16); lane i covers
    // row 16w + i/4, swizzled k-chunk (i&3)^((i>>3)&3).
    const int lr = lane >> 2;
    const int lc = (lane & 3) ^ ((lane >> 3) & 3);
    const size_t sbase = (size_t)(n0 + wave * 16 + lr) * LROW + lc * 8;
    // consume: row rf*16+m, want chunk q -> stored at q^((m>>1)&3)
    const int cq = (q ^ ((m >> 1) & 3)) * 8;

    f32x4 z = {0.f, 0.f, 0.f, 0.f};
    f32x4 acc[7][4];
#pragma unroll
    for (int t = 0; t < 7; t++)
#pragma unroll
        for (int rf = 0; rf < 4; rf++) acc[t][rf] = z;

    int woff[7];
#pragma unroll
    for (int t = 0; t < 7; t++)
        woff[t] = ((t * 4 + wave) * 16 + m) * 224 + q * 8;

#define STAGE(nb, KO)                                              \
    gl16(L0 + sbase + (KO), &U.lbuf[nb][0][wave * 16][0]);         \
    gl16(L1 + sbase + (KO), &U.lbuf[nb][1][wave * 16][0]);         \
    gl16(L2 + sbase + (KO), &U.lbuf[nb][2][wave * 16][0]);

#define GP(Wreg, Fr)                                               \
    _Pragma("unroll")                                              \
    for (int t = 0; t < 7; t++) {                                  \
        _Pragma("unroll")                                          \
        for (int rf = 0; rf < 4; rf++)                             \
            acc[t][rf] = mfma16(Wreg[t], Fr[rf], acc[t][rf]);      \
    }

    STAGE(0, 0)
    __syncthreads();

    short8 wA[7], wB[7];
#pragma unroll
    for (int t = 0; t < 7; t++) wA[t] = *(const short8*)(W0 + woff[t]);

#pragma unroll
    for (int kc = 0; kc < 7; kc++) {
        const int ko = kc * 32;
        const int cb = kc & 1;
        if (kc < 6) { STAGE(cb ^ 1, ko + 32) }

        short8 f0[4], f1[4], f2[4];
#pragma unroll
        for (int rf = 0; rf < 4; rf++)
            f0[rf] = *(const short8*)&U.lbuf[cb][0][rf * 16 + m][cq];
#pragma unroll
        for (int rf = 0; rf < 4; rf++)
            f1[rf] = *(const short8*)&U.lbuf[cb][1][rf * 16 + m][cq];
#pragma unroll
        for (int rf = 0; rf < 4; rf++)
            f2[rf] = *(const short8*)&U.lbuf[cb][2][rf * 16 + m][cq];

        if ((kc & 1) == 0) {           // W0 currently in wA
#pragma unroll
            for (int t = 0; t < 7; t++) wB[t] = *(const short8*)(W1 + woff[t] + ko);
            GP(wA, f0); GP(wA, f1); GP(wA, f2);          // W0 products
#pragma unroll
            for (int t = 0; t < 7; t++) wA[t] = *(const short8*)(W2 + woff[t] + ko);
            GP(wB, f0); GP(wB, f1);                      // W1 products
            if (kc < 6) {
#pragma unroll
                for (int t = 0; t < 7; t++) wB[t] = *(const short8*)(W0 + woff[t] + ko + 32);
            }
            GP(wA, f0);                                  // W2 product
        } else {                        // W0 currently in wB
#pragma unroll
            for (int t = 0; t < 7; t++) wA[t] = *(const short8*)(W1 + woff[t] + ko);
            GP(wB, f0); GP(wB, f1); GP(wB, f2);          // W0 products
#pragma unroll
            for (int t = 0; t < 7; t++) wB[t] = *(const short8*)(W2 + woff[t] + ko);
            GP(wA, f0); GP(wA, f1);                      // W1 products
            if (kc < 6) {
#pragma unroll
                for (int t = 0; t < 7; t++) wA[t] = *(const short8*)(W0 + woff[t] + ko + 32);
            }
            GP(wB, f0);                                  // W2 product
        }
        __syncthreads();   // kc+1 staging complete (issued ~815cy ago);
                           // all waves done reading buf cb -> reusable
    }
#undef GP
#undef STAGE

    // ---- epilogue phase A: cooperative hold reconstruction -> LDS fp32
#pragma unroll
    for (int p = 0; p < 4; p++) {
        int idx = tid + p * 256;          // 1024 slots: 64 rows x 16 chunks
        int row = idx >> 4, c = idx & 15;
        if (c < 13) {                     // cols [0,104): h[0,100) + zero pad
            size_t g = (size_t)(n0 + row) * LROW + 112 + c * 8;
            union { short8 s; ushort_t u[8]; } a0, a1, a2;
            a0.s = *(const short8*)(L0 + g);
            a1.s = *(const short8*)(L1 + g);
            a2.s = *(const short8*)(L2 + g);
#pragma unroll
            for (int j = 0; j < 8; j++)
                U.sh[row][c * 8 + j] =
                    (limb2f(a2.u[j]) + limb2f(a1.u[j])) + limb2f(a0.u[j]);
        }
    }
    __syncthreads();

    // ---- epilogue phase B: gates (each (row,d) owned by exactly one thread)
#pragma unroll
    for (int t = 0; t < 7; t++) {
        const int ct = t * 4 + wave;        // 0..27
        const int d = ct * 4 + q;           // 0..111
        if (d < 100) {
            float4 b4 = *(const float4*)&bg[ct * 16 + 4 * q];
#pragma unroll
            for (int rf = 0; rf < 4; rf++) {
                int row = rf * 16 + m;
                float hold = U.sh[row][d];
                float rp = acc[t][rf][0] + b4.x;
                float zp = acc[t][rf][1] + b4.y;
                float np = acc[t][rf][2] + b4.z;
                float hh = acc[t][rf][3] + b4.w;
                float rr = 1.f / (1.f + __expf(-rp));
                float zz = 1.f / (1.f + __expf(-zp));
                float nw = tanhf(np + rr * hh);
                U.sh[row][d] = (1.f - zz) * nw + zz * hold;
            }
        }
    }
    __syncthreads();

    // ---- epilogue phase C: cooperative split + vectorized 16B limb stores
#pragma unroll
    for (int p = 0; p < 4; p++) {
        int idx = tid + p * 256;
        int row = idx >> 4, c = idx & 15;
        if (c < 13) {
            size_t g = (size_t)(n0 + row) * LROW + 112 + c * 8;
            union { short8 s; uint32 u4[4]; } o0, o1, o2;
#pragma unroll
            for (int jj = 0; jj < 4; jj++) {
                float ea = U.sh[row][c * 8 + 2 * jj];
                float eb = U.sh[row][c * 8 + 2 * jj + 1];
                uint32 ha, ma, la, hb, mb, lb;
                split3(ea, ha, ma, la);
                split3(eb, hb, mb, lb);
                o0.u4[jj] = ha | (hb << 16);
                o1.u4[jj] = ma | (mb << 16);
                o2.u4[jj] = la | (lb << 16);
            }
            *(short8*)(L0 + g) = o0.s;
            *(short8*)(L1 + g) = o1.s;
            *(short8*)(L2 + g) = o2.s;
        }
    }
}

// ---------------------------------------------------------------- classifier
__global__ __launch_bounds__(256) void classifier(
    const ushort_t* __restrict__ L0, const ushort_t* __restrict__ L1,
    const ushort_t* __restrict__ L2, const float* __restrict__ W1,
    const float* __restrict__ b1, const float* __restrict__ W2,
    const float* __restrict__ b2, float* __restrict__ out) {
    __shared__ float Wc[3128];   // [3000,3128) zero pad: k in [100,104) rows
    __shared__ float bc[30];
    __shared__ float w2[30];
    int tid = threadIdx.x;
    for (int i = tid; i < 3128; i += 256) Wc[i] = (i < 3000) ? W1[i] : 0.f;
    if (tid < 30) { bc[tid] = b1[tid]; w2[tid] = W2[tid]; }
    __syncthreads();
    int n = blockIdx.x * 256 + tid;
    float a[30];
#pragma unroll
    for (int j = 0; j < 30; j++) a[j] = bc[j];
    const size_t base = (size_t)n * LROW + 112;
    for (int k8 = 0; k8 < 13; k8++) {     // k in [0,104); [100,104) limbs are 0
        int k0 = k8 * 8;
        union { short8 s; ushort_t u[8]; } h0, h1, h2;
        h0.s = *(const short8*)(L0 + base + k0);
        h1.s = *(const short8*)(L1 + base + k0);
        h2.s = *(const short8*)(L2 + base + k0);
#pragma unroll
        for (int jj = 0; jj < 8; jj++) {
            float hv = (limb2f(h2.u[jj]) + limb2f(h1.u[jj])) + limb2f(h0.u[jj]);
#pragma unroll
            for (int j = 0; j < 30; j++) a[j] = fmaf(hv, Wc[(k0 + jj) * 30 + j], a[j]);
        }
    }
    float s = b2[0];
#pragma unroll
    for (int j = 0; j < 30; j++) s = fmaf(fmaxf(a[j], 0.f), w2[j], s);
    out[n] = s;
}

// ---------------------------------------------------------------- launch
extern "C" void kernel_launch(void* const* d_in, const int* in_sizes, int n_in,
                              void* d_out, int out_size, void* d_ws, size_t ws_size,
                              hipStream_t stream) {
    const float* feat     = (const float*)d_in[0];
    const int*   er       = (const int*)d_in[1];
    const int*   ec       = (const int*)d_in[2];
    const float* init_W   = (const float*)d_in[3];
    const float* init_b   = (const float*)d_in[4];
    const float* fmsg_W1  = (const float*)d_in[5];
    const float* fmsg_b1  = (const float*)d_in[6];
    const float* fmsg_W2  = (const float*)d_in[7];
    const float* fmsg_b2  = (const float*)d_in[8];
    const float* bmsg_W1  = (const float*)d_in[9];
    const float* bmsg_b1  = (const float*)d_in[10];
    const float* bmsg_W2  = (const float*)d_in[11];
    const float* bmsg_b2  = (const float*)d_in[12];
    const float* fgru_Wih = (const float*)d_in[13];
    const float* fgru_Whh = (const float*)d_in[14];
    const float* fgru_bih = (const float*)d_in[15];
    const float* fgru_bhh = (const float*)d_in[16];
    const float* bgru_Wih = (const float*)d_in[17];
    const float* bgru_Whh = (const float*)d_in[18];
    const float* bgru_bih = (const float*)d_in[19];
    const float* bgru_bhh = (const float*)d_in[20];
    const float* cls_W1   = (const float*)d_in[21];
    const float* cls_b1   = (const float*)d_in[22];
    const float* cls_W2   = (const float*)d_in[23];
    const float* cls_b2   = (const float*)d_in[24];
    float* out = (float*)d_out;

    // Workspace budget (256 MiB hard limit):
    //   fm          52.43 MB
    //   limb planes 176.16 MB (3 x (Nn*224+64) shorts)
    //   weights     ~1.39 MB, biases ~5 KB
    //   CSR ints    ~6.29 MB
    //   total      ~236.3 MB  OK
    float* ws = (float*)d_ws;
    size_t o = 0;
    float* fm = ws + o; o += (size_t)Nn * 100;            // [N][100] fp32

    const size_t PL = (size_t)Nn * LROW + 64;             // limb plane size (shorts)
    ushort_t* us = (ushort_t*)(ws + o);
    size_t uo = 0;
    ushort_t* L0 = us + uo; uo += PL;
    ushort_t* L1 = us + uo; uo += PL;
    ushort_t* L2 = us + uo; uo += PL;
    ushort_t* fWg0 = us + uo; uo += 448 * 224;
    ushort_t* fWg1 = us + uo; uo += 448 * 224;
    ushort_t* fWg2 = us + uo; uo += 448 * 224;
    ushort_t* bWg0 = us + uo; uo += 448 * 224;
    ushort_t* bWg1 = us + uo; uo += 448 * 224;
    ushort_t* bWg2 = us + uo; uo += 448 * 224;
    ushort_t* fA0 = us + uo; uo += 8192;
    ushort_t* fA1 = us + uo; uo += 8192;
    ushort_t* fA2 = us + uo; uo += 8192;
    ushort_t* bA0 = us + uo; uo += 8192;
    ushort_t* bA1 = us + uo; uo += 8192;
    ushort_t* bA2 = us + uo; uo += 8192;
    ushort_t* fB0 = us + uo; uo += 7168;
    ushort_t* fB1 = us + uo; uo += 7168;
    ushort_t* fB2 = us + uo; uo += 7168;
    ushort_t* bB0 = us + uo; uo += 7168;
    ushort_t* bB1 = us + uo; uo += 7168;
    ushort_t* bB2 = us + uo; uo += 7168;     // uo even
    o += uo / 2;

    float* bgf  = ws + o; o += 448;
    float* bgb  = ws + o; o += 448;
    float* b1pf = ws + o; o += 64;
    float* b1pb = ws + o; o += 64;
    float* b2pf = ws + o; o += 112;
    float* b2pb = ws + o; o += 112;

    int* iws   = (int*)(ws + o);
    int* ptr_f = iws;                       // N+1
    int* ptr_b = ptr_f + (Nn + 1);          // N+1
    int* cnt   = ptr_b + (Nn + 1);          // 2N
    int* cnt_f = cnt;
    int* cnt_b = cnt + Nn;
    int* src_f = cnt + 2 * (size_t)Nn;      // E
    int* src_b = src_f + Ee;                // E

    size_t need = o * sizeof(float) +
                  (size_t)(2 * (Nn + 1) + 2 * Nn + 2 * Ee) * sizeof(int);
    if (ws_size < need) {
        diag_kernel<<<(Nn + 255) / 256, 256, 0, stream>>>(out, (float)ws_size);
        return;
    }

    // zero limb planes once (pads [100,112) and [212,224) must stay 0; tail pad)
    {
        long n8 = (long)(3 * PL / 8);
        zero_short8<<<(int)((n8 + 255) / 256), 256, 0, stream>>>(L0, n8);
    }

    // CSR build
    zero_ints<<<(2 * Nn + 255) / 256, 256, 0, stream>>>(cnt, 2 * Nn);
    hist_kernel<<<Ee / 256, 256, 0, stream>>>(er, ec, cnt_f, cnt_b);
    scan2_kernel<<<2, 1024, 0, stream>>>(cnt_f, cnt_b, ptr_f, ptr_b, Nn);
    fill_kernel<<<Ee / 256, 256, 0, stream>>>(er, ec, ptr_f, ptr_b, src_f, src_b);

    // weight prep (split to 3 bf16 limbs)
    prep_gru_w<<<(448 * 224 + 255) / 256, 256, 0, stream>>>(
        fgru_Wih, fgru_Whh, fgru_bih, fgru_bhh, fWg0, fWg1, fWg2, bgf);
    prep_gru_w<<<(448 * 224 + 255) / 256, 256, 0, stream>>>(
        bgru_Wih, bgru_Whh, bgru_bih, bgru_bhh, bWg0, bWg1, bWg2, bgb);
    prep_msg_w<<<(15360 + 255) / 256, 256, 0, stream>>>(
        fmsg_W1, fmsg_b1, fmsg_W2, fmsg_b2, fA0, fA1, fA2, b1pf, fB0, fB1, fB2, b2pf);
    prep_msg_w<<<(15360 + 255) / 256, 256, 0, stream>>>(
        bmsg_W1, bmsg_b1, bmsg_W2, bmsg_b2, bA0, bA1, bA2, b1pb, bB0, bB1, bB2, b2pb);

    // h init (writes h limbs)
    init_h_kernel<<<(Nn * 100 + 255) / 256, 256, 0, stream>>>(
        feat, init_W, init_b, L0, L1, L2);

    const int gTile = Nn / 64;            // 2048 (msg)
    const int gGru  = Nn / 64;            // 2048 (gru, 64 rows/block, 256 thr)
    const int gGath = Nn * 25 / 256;      // 12800

    for (int rd = 0; rd < 20; rd++) {
        msg_mfma<<<gTile, 256, 0, stream>>>(L0, L1, L2,
            fA0, fA1, fA2, b1pf, fB0, fB1, fB2, b2pf, fm);
        gather4<<<gGath, 256, 0, stream>>>(fm, ptr_f, src_f, L0, L1, L2);
        gru_mfma<<<gGru, 256, 0, stream>>>(L0, L1, L2, fWg0, fWg1, fWg2, bgf);

        msg_mfma<<<gTile, 256, 0, stream>>>(L0, L1, L2,
            bA0, bA1, bA2, b1pb, bB0, bB1, bB2, b2pb, fm);
        gather4<<<gGath, 256, 0, stream>>>(fm, ptr_b, src_b, L0, L1, L2);
        gru_mfma<<<gGru, 256, 0, stream>>>(L0, L1, L2, bWg0, bWg1, bWg2, bgb);
    }

    classifier<<<Nn / 256, 256, 0, stream>>>(L0, L1, L2,
        cls_W1, cls_b1, cls_W2, cls_b2, out);
}